// Round 11
// baseline (384.810 us; speedup 1.0000x reference)
//
#include <hip/hip_runtime.h>

// Problem: B=4, N=2048, C=768, H=12, D=64. I/O f32; internals bf16 MFMA + f32 acc.
// Pipeline: LN(f32->bf16) -> QKV GEMM (Q*0.125*log2e, K [B,H,N,D]; V^T fused) ->
//           flash attention -> out-proj GEMM (+bias +residual).
// R22: attn K via per-wave REGISTER loads (L1 path), V stays LDS-staged.
//   R21 counters: LDS port ~88% busy (147K of 166K cyc) -> port-bound. Split
//   K onto the idle L1 port (24KB working set fits 32KB L1; L2 traffic stays
//   compulsory). kr[8] (32 VGPR; base was 32 -> ~70 total, no spill at (512,6)
//   cap 85). Each chunk's kr quartet reloaded for it+1 right after its QK
//   (full-iteration cover, compiler-tracked deps). Only V needs the explicit
//   gate: queue at top of it = {V(it), kr x8, V(it+1)} -> vmcnt(9)
//   (it=0: vmcnt(1); it=31: vmcnt(8)). LDS 32KB -> 16KB.
//   GEMMs = R19 best-total config (BK=64 2-stage, XCD swizzle).

typedef __bf16 bf16x8 __attribute__((ext_vector_type(8)));
typedef float  f32x4  __attribute__((ext_vector_type(4)));
typedef unsigned int u32x4 __attribute__((ext_vector_type(4)));

#define MFMA16(a,b,c) __builtin_amdgcn_mfma_f32_16x16x32_bf16((a),(b),(c),0,0,0)

__device__ inline f32x4 zero4() { f32x4 z = {0.f,0.f,0.f,0.f}; return z; }

// async global->LDS, 16B per lane; lds dest is wave-uniform base + lane*16
__device__ inline void gll16(const __bf16* g, __bf16* l) {
  __builtin_amdgcn_global_load_lds((const __attribute__((address_space(1))) unsigned int*)g,
                                   (__attribute__((address_space(3))) unsigned int*)l,
                                   16, 0, 0);
}

// pack two f32 -> bf16x2 (RNE); no builtin on gfx950, inline asm per guide
__device__ inline unsigned cvt_pk_bf16(float lo, float hi) {
  unsigned r;
  asm("v_cvt_pk_bf16_f32 %0, %1, %2" : "=v"(r) : "v"(lo), "v"(hi));
  return r;
}
// a[32:63] <-> b[0:31]
__device__ inline void permlane32_swap(unsigned &a, unsigned &b) {
  asm("v_permlane32_swap_b32 %0, %1" : "+v"(a), "+v"(b));
}
// a[16:31]<->b[0:15], a[48:63]<->b[32:47]
__device__ inline void permlane16_swap(unsigned &a, unsigned &b) {
  asm("v_permlane16_swap_b32 %0, %1" : "+v"(a), "+v"(b));
}

// ---------------- LayerNorm: one block per row of 768; f32 in, bf16 out ----------------
__global__ __launch_bounds__(256) void ln_kernel(const float* __restrict__ x,
                                                 const float* __restrict__ g,
                                                 const float* __restrict__ bt,
                                                 __bf16* __restrict__ xn) {
  const int row = blockIdx.x;
  const int tid = threadIdx.x;
  const float* xr = x + (size_t)row * 768;
  float v[3]; float s = 0.f, ss = 0.f;
  #pragma unroll
  for (int i = 0; i < 3; ++i) { float f = xr[tid + 256*i]; v[i] = f; s += f; ss += f*f; }
  #pragma unroll
  for (int m = 32; m >= 1; m >>= 1) { s += __shfl_xor(s, m, 64); ss += __shfl_xor(ss, m, 64); }
  __shared__ float red[8];
  const int wave = tid >> 6;
  if ((tid & 63) == 0) { red[wave] = s; red[4 + wave] = ss; }
  __syncthreads();
  s  = red[0] + red[1] + red[2] + red[3];
  ss = red[4] + red[5] + red[6] + red[7];
  const float mu  = s * (1.f/768.f);
  const float var = ss * (1.f/768.f) - mu*mu;
  const float inv = rsqrtf(var + 1e-5f);
  __bf16* xo = xn + (size_t)row * 768;
  #pragma unroll
  for (int i = 0; i < 3; ++i) {
    const int c0 = tid + 256*i;
    xo[c0] = (__bf16)((v[i] - mu) * inv * g[c0] + bt[c0]);
  }
}

// ---------------- 32x32 tiled transpose + f32->bf16: in[R][C] f32 -> out[C][R] bf16 ----------------
__global__ __launch_bounds__(256) void transpose_kernel(const float* __restrict__ in,
                                                        __bf16* __restrict__ out,
                                                        int R, int C) {
  __shared__ float t[32][33];
  const int tx = threadIdx.x & 31, ty = threadIdx.x >> 5;
  const int c0 = blockIdx.x * 32, r0 = blockIdx.y * 32;
  #pragma unroll
  for (int p = 0; p < 4; ++p) t[ty + 8*p][tx] = in[(size_t)(r0 + ty + 8*p) * C + c0 + tx];
  __syncthreads();
  #pragma unroll
  for (int p = 0; p < 4; ++p) out[(size_t)(c0 + ty + 8*p) * R + r0 + tx] = (__bf16)t[tx][ty + 8*p];
}

// ---------------- GEMM mainloop BK=64, double-buffered: C[128x128] = A @ BT^T (bf16) ----
// LDS per buffer: 16 subtiles of 16x32 per operand (st = rowblk*2 + khalf, 1KB each);
// two buffers per operand (64KB total). Wave stages 4 A + 4 B subtiles (8 gll16).
// Steady state: compute buf[t&1] while stage(t+1)'s 8 loads are in flight
// (vmcnt(8) at top, never 0 mid-loop); stage(t+2) issued after the read-done barrier.
template<int KDIM>
__device__ inline void gemm_mainloop(const __bf16* __restrict__ A, const __bf16* __restrict__ BT,
                                     int bm, int bn, int wave, int lane,
                                     f32x4 acc[4][4], __bf16* Asm, __bf16* Bsm) {
  const int wm = wave >> 1, wn = wave & 1;
  const int lr = lane & 15, lk = lane >> 4;
  constexpr int NIT = KDIM / 64;
  auto stage = [&](int t) {
    const int k0 = t * 64;
    __bf16* Ad = Asm + (t & 1) * 8192;
    __bf16* Bd = Bsm + (t & 1) * 8192;
    #pragma unroll
    for (int s2 = 0; s2 < 4; ++s2) {
      const int st = wave * 4 + s2;
      const int rb = st >> 1, kh = st & 1;
      gll16(A  + (size_t)(bm + rb*16 + lr) * KDIM + k0 + kh*32 + lk*8, Ad + st*512);
      gll16(BT + (size_t)(bn + rb*16 + lr) * KDIM + k0 + kh*32 + lk*8, Bd + st*512);
    }
  };
  stage(0);
  stage(1);
  for (int t = 0; t < NIT; ++t) {
    // own stage(t) loads retired once outstanding <= 8 (stage(t+1) still in flight)
    if (t + 1 < NIT) asm volatile("s_waitcnt vmcnt(8)" ::: "memory");
    else             asm volatile("s_waitcnt vmcnt(0)" ::: "memory");
    asm volatile("s_barrier" ::: "memory");      // all waves' stage(t) visible
    const __bf16* Ab = Asm + (t & 1) * 8192;
    const __bf16* Bb = Bsm + (t & 1) * 8192;
    #pragma unroll
    for (int ks = 0; ks < 2; ++ks) {
      bf16x8 a[4], b[4];
      #pragma unroll
      for (int mt = 0; mt < 4; ++mt) a[mt] = *(const bf16x8*)(Ab + ((wm*4+mt)*2+ks)*512 + lane*8);
      #pragma unroll
      for (int nt = 0; nt < 4; ++nt) b[nt] = *(const bf16x8*)(Bb + ((wn*4+nt)*2+ks)*512 + lane*8);
      __builtin_amdgcn_s_setprio(1);
      #pragma unroll
      for (int mt = 0; mt < 4; ++mt)
        #pragma unroll
        for (int nt = 0; nt < 4; ++nt)
          acc[mt][nt] = MFMA16(a[mt], b[nt], acc[mt][nt]);
      __builtin_amdgcn_s_setprio(0);
    }
    asm volatile("s_barrier" ::: "memory");      // all waves done reading buf[t&1]
    if (t + 2 < NIT) stage(t + 2);               // overwrite buf[t&1] for t+2
  }
}

// ---------------- QKV GEMM: xn[8192,768] @ wqkvT[2304,768]^T ----------------
// Q/K blocks (bn<1536) store direct. V blocks (bn>=1536) transpose the 128x128 acc
// tile in LDS (pad-66) and store V^T [B,H,D,N] coalesced. Transpose tile aliases staging.
// Grid: 1152 linear blocks, XCD-swizzled: each XCD gets 144 contiguous work items
// = 8 bm-rows x 18 bn-cols -> B panel (3.5MB) ~resident in its 4MB L2.
__global__ __launch_bounds__(256) void gemm_qkv_kernel(const __bf16* __restrict__ A,
                                                       const __bf16* __restrict__ BT,
                                                       __bf16* __restrict__ q,
                                                       __bf16* __restrict__ k,
                                                       __bf16* __restrict__ vt) {
  __shared__ __align__(16) __bf16 smem[4*8192];   // A dbuf + B dbuf (64KB); aliased transpose tile
  __bf16* Asm = smem;
  __bf16* Bsm = smem + 2*8192;
  const int lane = threadIdx.x & 63, wave = threadIdx.x >> 6;
  // XCD swizzle: 1152 blocks, 144 per XCD (bijective since 1152%8==0)
  const int wg = (blockIdx.x & 7) * 144 + (blockIdx.x >> 3);
  const int bm = (wg / 18) * 128, bn = (wg % 18) * 128;
  f32x4 acc[4][4];
  #pragma unroll
  for (int i = 0; i < 4; ++i)
    #pragma unroll
    for (int j = 0; j < 4; ++j) acc[i][j] = zero4();
  gemm_mainloop<768>(A, BT, bm, bn, wave, lane, acc, Asm, Bsm);
  const int wm = wave >> 1, wn = wave & 1;
  const int quad = lane >> 4, c = lane & 15;
  if (bn < 1536) {
    // Q pre-scale: 1/sqrt(64) * log2(e) so attention does p = exp2(score) natively
    const float qscale = 0.125f * 1.44269504088896f;
    #pragma unroll
    for (int mt = 0; mt < 4; ++mt)
      #pragma unroll
      for (int nt = 0; nt < 4; ++nt) {
        const int col = bn + wn*64 + nt*16 + c;           // 0..1535
        const int which = col >= 768 ? 1 : 0;
        const int within = col - which*768;
        const int h = within >> 6, d = within & 63;
        #pragma unroll
        for (int r = 0; r < 4; ++r) {
          const int row = bm + wm*64 + mt*16 + quad*4 + r; // 0..8191
          const int b = row >> 11, n = row & 2047;
          const float vv = acc[mt][nt][r];
          const size_t idx = ((size_t)(b*12 + h) * 2048 + n) * 64 + d;  // [B,H,N,D]
          if (which == 0) q[idx] = (__bf16)(vv * qscale);
          else            k[idx] = (__bf16)vv;
        }
      }
  } else {
    __syncthreads();   // staging buffers dead; reuse as transpose tile
    #pragma unroll
    for (int mt = 0; mt < 4; ++mt)
      #pragma unroll
      for (int nt = 0; nt < 4; ++nt) {
        const int lcol = wn*64 + nt*16 + c;
        #pragma unroll
        for (int r = 0; r < 4; ++r) {
          const int lrow = wm*64 + mt*16 + quad*4 + r;
          smem[lrow*66 + lcol] = (__bf16)acc[mt][nt][r];
        }
      }
    __syncthreads();
    const int b = bm >> 11, n0 = bm & 2047;
    const int vo = bn - 1536;                // 0..639 (V-region col offset)
    const int n = threadIdx.x & 127;
    const int csel = threadIdx.x >> 7;
    #pragma unroll
    for (int pass = 0; pass < 64; ++pass) {
      const int lc = pass*2 + csel;          // 0..127
      const int gcol = vo + lc;              // 0..767
      const int h = gcol >> 6, d = gcol & 63;
      vt[((size_t)(b*12 + h)*64 + d)*2048 + n0 + n] = smem[n*66 + lc];
    }
  }
}

// ---------------- Out-proj GEMM: o[8192,768] @ woutT[768,768]^T + f32 bias + f32 residual ----------------
// Grid: 384 linear blocks, XCD-swizzled (48/XCD = 8 bm-rows x 6 bn-cols; B 1.1MB in L2).
__global__ __launch_bounds__(256) void gemm_out_kernel(const __bf16* __restrict__ A,
                                                       const __bf16* __restrict__ BT,
                                                       const float* __restrict__ bias,
                                                       const float* __restrict__ resid,
                                                       float* __restrict__ out) {
  __shared__ __align__(16) __bf16 Asm[2*8192];
  __shared__ __align__(16) __bf16 Bsm[2*8192];
  const int lane = threadIdx.x & 63, wave = threadIdx.x >> 6;
  // XCD swizzle: 384 blocks, 48 per XCD (bijective since 384%8==0)
  const int wg = (blockIdx.x & 7) * 48 + (blockIdx.x >> 3);
  const int bm = (wg / 6) * 128, bn = (wg % 6) * 128;
  f32x4 acc[4][4];
  #pragma unroll
  for (int i = 0; i < 4; ++i)
    #pragma unroll
    for (int j = 0; j < 4; ++j) acc[i][j] = zero4();
  gemm_mainloop<768>(A, BT, bm, bn, wave, lane, acc, Asm, Bsm);
  const int wm = wave >> 1, wn = wave & 1;
  const int quad = lane >> 4, c = lane & 15;
  #pragma unroll
  for (int mt = 0; mt < 4; ++mt)
    #pragma unroll
    for (int nt = 0; nt < 4; ++nt) {
      const int col = bn + wn*64 + nt*16 + c;
      #pragma unroll
      for (int r = 0; r < 4; ++r) {
        const int row = bm + wm*64 + mt*16 + quad*4 + r;
        out[(size_t)row*768 + col] = acc[mt][nt][r] + bias[col] + resid[(size_t)row*768 + col];
      }
    }
}

// ---------------- Flash attention: 1 block = (b,h) x 128 q-rows; 8 waves x 16 rows ----
// Swapped QK^T: S^T = mfma(K, Q); lane's S regs are its own q-row (lane&15).
// K in REGISTERS kr[8] (per-wave global loads through L1; same per-lane mapping
// as the old gll16 source -> fragment layout unchanged). Each chunk's kr quartet
// reloaded for it+1 right after its QK consumes it (full-iter cover, compiler-
// tracked deps). V LDS-staged dbuf (1 gll16/wave/stage, 16KB). Explicit gate only
// for V: queue at top of it = {V(it), kr x8, V(it+1)} -> vmcnt(9) (it=0: 1; it=31: 8).
// p = exp2(s) in-register; P->bf16 via cvt_pk + permlane32/16_swap; row-sum via
// ones-operand MFMA (clacc, od layout).
__global__ __launch_bounds__(512, 6) void attn_kernel(const __bf16* __restrict__ q,
                                                      const __bf16* __restrict__ k,
                                                      const __bf16* __restrict__ vt,
                                                      __bf16* __restrict__ o) {
  // XCD swizzle: 768 blocks -> 96/XCD = 6 whole (b,h) groups of 16 q-tiles;
  // K/V (512KB each) stays in the XCD's 4MB L2.
  const int xcd = blockIdx.x & 7, i = blockIdx.x >> 3;
  const int bh = xcd * 6 + (i >> 4);   // 0..47
  const int qt = i & 15;               // 16 q-tiles of 128 rows
  const int lane = threadIdx.x & 63, wave = threadIdx.x >> 6;   // wave 0..7
  const int c = lane & 15, quad = lane >> 4;
  const int lr = lane & 15, lk = lane >> 4;
  const int q0 = qt*128 + wave*16;

  const __bf16* qb = q  + ((size_t)bh*2048 + q0) * 64;
  const __bf16* kb = k  + (size_t)bh * 2048 * 64;
  const __bf16* vb = vt + (size_t)bh * 64 * 2048;

  __shared__ __align__(16) __bf16 Vsm[2][4096];

  // Q B-frags (row = c) — Q pre-scaled by 0.125*log2e
  bf16x8 aq[2];
  aq[0] = *(const bf16x8*)(qb + (size_t)c*64 + quad*8);
  aq[1] = *(const bf16x8*)(qb + (size_t)c*64 + 32 + quad*8);

  // ones B-frag for row-sum MFMA
  const __bf16 one = (__bf16)1.0f;
  bf16x8 vones;
  #pragma unroll
  for (int j = 0; j < 8; ++j) vones[j] = one;

  f32x4 od[4];
  f32x4 clacc = zero4();       // row-sum acc; D layout row = quad*4+r (matches od)
  #pragma unroll
  for (int r = 0; r < 4; ++r) od[r] = zero4();

  // K fragment registers: kr[st] = K[kt + (st>>1)*16 + lr][(st&1)*32 + lk*8 ..+8]
  // (identical per-lane mapping to the old LDS-staged A-frag).
  bf16x8 kr[8];
  #pragma unroll
  for (int st = 0; st < 8; ++st)
    kr[st] = *(const bf16x8*)(kb + (size_t)((st>>1)*16 + lr) * 64 + (st&1)*32 + lk*8);

  // V stage: 8 subtiles over 8 waves, 1 gll16 each. st = wave:
  // dblock = wave>>1 (d rows), keyhalf = wave&1.
  auto stageV = [&](int it) {
    const int kt = it * 64;
    gll16(vb + (size_t)((wave>>1)*16 + lr) * 2048 + kt + (wave&1)*32 + lk*8,
          Vsm[it & 1] + wave*512);
  };

  stageV(0);
  stageV(1);

  for (int it = 0; it < 32; ++it) {
    const __bf16* Vs = Vsm[it & 1];
    const int ktn = (it + 1) * 64;           // next iter's K base
    // gate: own V(it) DMA retired. Per-wave VMEM queue newer than V(it):
    // kr(it) x8 (issued during it-1) + V(it+1) (end of it-1) = 9.
    // it==0: prologue queue [aq,kr(0)x8,V(0),V(1)] -> newer-than-V(0)=1.
    // it==31: no V(32) staged -> 8.
    if (it == 0)      asm volatile("s_waitcnt vmcnt(1)" ::: "memory");
    else if (it < 31) asm volatile("s_waitcnt vmcnt(9)" ::: "memory");
    else              asm volatile("s_waitcnt vmcnt(8)" ::: "memory");
    asm volatile("s_barrier" ::: "memory");
    #pragma unroll
    for (int ch = 0; ch < 2; ++ch) {         // 32-key chunks; chunk ch uses kr[4ch..4ch+3]
      // S^T over this chunk's 2 key-subtiles; P packed to bf16.
      unsigned pk[2][2];
      #pragma unroll
      for (int t2 = 0; t2 < 2; ++t2) {
        const int t = ch*2 + t2;
        f32x4 z = zero4();
        __builtin_amdgcn_s_setprio(1);
        z = MFMA16(kr[t*2+0], aq[0], z);
        z = MFMA16(kr[t*2+1], aq[1], z);
        __builtin_amdgcn_s_setprio(0);
        const float p0 = __builtin_amdgcn_exp2f(z[0]);
        const float p1 = __builtin_amdgcn_exp2f(z[1]);
        const float p2 = __builtin_amdgcn_exp2f(z[2]);
        const float p3 = __builtin_amdgcn_exp2f(z[3]);
        pk[t2][0] = cvt_pk_bf16(p0, p1);
        pk[t2][1] = cvt_pk_bf16(p2, p3);
      }
      // this chunk's kr quartet is dead -> reload for it+1 (L1-resident tile;
      // latency hidden under the rest of this iteration)
      if (it < 31) {
        #pragma unroll
        for (int j = 0; j < 4; ++j) {
          const int st = ch*4 + j;
          kr[st] = *(const bf16x8*)(kb + (size_t)(ktn + (st>>1)*16 + lr) * 64 + (st&1)*32 + lk*8);
        }
      }
      // Build PV A-frag: lane (c,quad) must hold keys quad*8+{0..7} for qrow c.
      unsigned s0 = pk[0][0], s2 = pk[1][0];
      permlane32_swap(s0, s2);
      permlane16_swap(s0, s2);
      unsigned s1 = pk[0][1], s3 = pk[1][1];
      permlane32_swap(s1, s3);
      permlane16_swap(s1, s3);
      u32x4 w4; w4.x = s0; w4.y = s1; w4.z = s2; w4.w = s3;
      const bf16x8 pa = __builtin_bit_cast(bf16x8, w4);
      // O += P V over this chunk's keys; row-sum += P * ones
      __builtin_amdgcn_s_setprio(1);
      #pragma unroll
      for (int dt = 0; dt < 4; ++dt) {
        const bf16x8 bv = *(const bf16x8*)(Vs + (dt*2+ch)*512 + lane*8);
        od[dt] = MFMA16(pa, bv, od[dt]);
      }
      clacc = MFMA16(pa, vones, clacc);
      __builtin_amdgcn_s_setprio(0);
    }
    asm volatile("s_barrier" ::: "memory");   // all waves done reading Vsm[it&1]
    if (it + 2 < 32) stageV(it + 2);
  }
  const int b = bh / 12, h = bh % 12;
  float rl[4];
  #pragma unroll
  for (int r = 0; r < 4; ++r) rl[r] = 1.f / clacc[r];
  #pragma unroll
  for (int dt = 0; dt < 4; ++dt)
    #pragma unroll
    for (int r = 0; r < 4; ++r) {
      const int n = q0 + quad*4 + r;
      const int col = h*64 + dt*16 + c;
      o[((size_t)b*2048 + n)*768 + col] = (__bf16)(od[dt][r] * rl[r]);
    }
}

extern "C" void kernel_launch(void* const* d_in, const int* in_sizes, int n_in,
                              void* d_out, int out_size, void* d_ws, size_t ws_size,
                              hipStream_t stream) {
  const float* img   = (const float*)d_in[0];
  const float* gamma = (const float*)d_in[1];
  const float* beta  = (const float*)d_in[2];
  const float* wqkv  = (const float*)d_in[3];
  const float* wout  = (const float*)d_in[4];
  const float* bout  = (const float*)d_in[5];
  float* out = (float*)d_out;

  __bf16* ws = (__bf16*)d_ws;
  size_t off = 0;
  __bf16* xn    = ws + off; off += (size_t)8192*768;   // LN output (bf16)
  __bf16* wqkvT = ws + off; off += (size_t)2304*768;   // w_qkv^T (bf16)
  __bf16* woutT = ws + off; off += (size_t)768*768;    // w_out^T (bf16)
  __bf16* qs    = ws + off; off += (size_t)48*2048*64; // Q*0.125*log2e [B,H,N,D]
  __bf16* ks    = ws + off; off += (size_t)48*2048*64; // K     [B,H,N,D]
  __bf16* vts   = ws + off; off += (size_t)48*64*2048; // V^T   [B,H,D,N]
  __bf16* os    = ws + off; off += (size_t)8192*768;   // attn out [B,N,C]

  ln_kernel<<<8192, 256, 0, stream>>>(img, gamma, beta, xn);
  transpose_kernel<<<dim3(72, 24), 256, 0, stream>>>(wqkv, wqkvT, 768, 2304);
  transpose_kernel<<<dim3(24, 24), 256, 0, stream>>>(wout, woutT, 768, 768);
  gemm_qkv_kernel<<<1152, 256, 0, stream>>>(xn, wqkvT, qs, ks, vts);
  attn_kernel<<<768, 512, 0, stream>>>(qs, ks, vts, os);
  gemm_out_kernel<<<384, 256, 0, stream>>>(os, woutT, bout, img, out);
}

// Round 12
// 243.913 us; speedup vs baseline: 1.5777x; 1.5777x over previous
//
#include <hip/hip_runtime.h>

// Problem: B=4, N=2048, C=768, H=12, D=64. I/O f32; internals bf16 MFMA + f32 acc.
// Pipeline: LN(f32->bf16) -> QKV GEMM (Q*0.125*log2e, K [B,H,N,D]; V^T fused) ->
//           flash attention -> out-proj GEMM (+bias +residual).
// R23: gemm_qkv ported to the 256^2 8-phase schedule (T3+T4). Three 2-phase
//   variants all hit 67us / MfmaUtil 16% = the documented 2-phase ceiling
//   (~72% stage+vmcnt+barrier overhead). New: BM=BN=256, BK=64, 8 waves
//   (2M x 4N), 128KB LDS (2buf x 2half per operand), 4 phases per K-tile
//   {ds-reads; stage 1 half-tile (2 gll16); [vmcnt(4) @q3]; barrier; 16 MFMA
//   (quadrant mh,nh); barrier}. Stage stream during tile T: A(T+1)h1, B(T+1)h1,
//   A(T+2)h0, B(T+2)h0 -> each half overwritten only after its last reader
//   phase; single vmcnt(4) gate per tile covers the next tile (4-6 phases of
//   cover). Conflict-free 16x32-subtile LDS layout (no swizzle needed; measured
//   0 conflicts). Waves own split 64-row strips per half so halves free early.
//   attn/gemm_out/ln = R19 (proven 239.4us config). R22 closed the K-in-regs
//   arc: +32 VGPR spills at this occupancy and poisons vmcnt counts.

typedef __bf16 bf16x8 __attribute__((ext_vector_type(8)));
typedef float  f32x4  __attribute__((ext_vector_type(4)));
typedef unsigned int u32x4 __attribute__((ext_vector_type(4)));

#define MFMA16(a,b,c) __builtin_amdgcn_mfma_f32_16x16x32_bf16((a),(b),(c),0,0,0)

__device__ inline f32x4 zero4() { f32x4 z = {0.f,0.f,0.f,0.f}; return z; }

// async global->LDS, 16B per lane; lds dest is wave-uniform base + lane*16
__device__ inline void gll16(const __bf16* g, __bf16* l) {
  __builtin_amdgcn_global_load_lds((const __attribute__((address_space(1))) unsigned int*)g,
                                   (__attribute__((address_space(3))) unsigned int*)l,
                                   16, 0, 0);
}

// pack two f32 -> bf16x2 (RNE); no builtin on gfx950, inline asm per guide
__device__ inline unsigned cvt_pk_bf16(float lo, float hi) {
  unsigned r;
  asm("v_cvt_pk_bf16_f32 %0, %1, %2" : "=v"(r) : "v"(lo), "v"(hi));
  return r;
}
// a[32:63] <-> b[0:31]
__device__ inline void permlane32_swap(unsigned &a, unsigned &b) {
  asm("v_permlane32_swap_b32 %0, %1" : "+v"(a), "+v"(b));
}
// a[16:31]<->b[0:15], a[48:63]<->b[32:47]
__device__ inline void permlane16_swap(unsigned &a, unsigned &b) {
  asm("v_permlane16_swap_b32 %0, %1" : "+v"(a), "+v"(b));
}

// ---------------- LayerNorm: one block per row of 768; f32 in, bf16 out ----------------
__global__ __launch_bounds__(256) void ln_kernel(const float* __restrict__ x,
                                                 const float* __restrict__ g,
                                                 const float* __restrict__ bt,
                                                 __bf16* __restrict__ xn) {
  const int row = blockIdx.x;
  const int tid = threadIdx.x;
  const float* xr = x + (size_t)row * 768;
  float v[3]; float s = 0.f, ss = 0.f;
  #pragma unroll
  for (int i = 0; i < 3; ++i) { float f = xr[tid + 256*i]; v[i] = f; s += f; ss += f*f; }
  #pragma unroll
  for (int m = 32; m >= 1; m >>= 1) { s += __shfl_xor(s, m, 64); ss += __shfl_xor(ss, m, 64); }
  __shared__ float red[8];
  const int wave = tid >> 6;
  if ((tid & 63) == 0) { red[wave] = s; red[4 + wave] = ss; }
  __syncthreads();
  s  = red[0] + red[1] + red[2] + red[3];
  ss = red[4] + red[5] + red[6] + red[7];
  const float mu  = s * (1.f/768.f);
  const float var = ss * (1.f/768.f) - mu*mu;
  const float inv = rsqrtf(var + 1e-5f);
  __bf16* xo = xn + (size_t)row * 768;
  #pragma unroll
  for (int i = 0; i < 3; ++i) {
    const int c0 = tid + 256*i;
    xo[c0] = (__bf16)((v[i] - mu) * inv * g[c0] + bt[c0]);
  }
}

// ---------------- 32x32 tiled transpose + f32->bf16: in[R][C] f32 -> out[C][R] bf16 ----------------
__global__ __launch_bounds__(256) void transpose_kernel(const float* __restrict__ in,
                                                        __bf16* __restrict__ out,
                                                        int R, int C) {
  __shared__ float t[32][33];
  const int tx = threadIdx.x & 31, ty = threadIdx.x >> 5;
  const int c0 = blockIdx.x * 32, r0 = blockIdx.y * 32;
  #pragma unroll
  for (int p = 0; p < 4; ++p) t[ty + 8*p][tx] = in[(size_t)(r0 + ty + 8*p) * C + c0 + tx];
  __syncthreads();
  #pragma unroll
  for (int p = 0; p < 4; ++p) out[(size_t)(c0 + ty + 8*p) * R + r0 + tx] = (__bf16)t[tx][ty + 8*p];
}

// ---------------- GEMM mainloop BK=64, double-buffered (128x128; used by gemm_out) ----
template<int KDIM>
__device__ inline void gemm_mainloop(const __bf16* __restrict__ A, const __bf16* __restrict__ BT,
                                     int bm, int bn, int wave, int lane,
                                     f32x4 acc[4][4], __bf16* Asm, __bf16* Bsm) {
  const int wm = wave >> 1, wn = wave & 1;
  const int lr = lane & 15, lk = lane >> 4;
  constexpr int NIT = KDIM / 64;
  auto stage = [&](int t) {
    const int k0 = t * 64;
    __bf16* Ad = Asm + (t & 1) * 8192;
    __bf16* Bd = Bsm + (t & 1) * 8192;
    #pragma unroll
    for (int s2 = 0; s2 < 4; ++s2) {
      const int st = wave * 4 + s2;
      const int rb = st >> 1, kh = st & 1;
      gll16(A  + (size_t)(bm + rb*16 + lr) * KDIM + k0 + kh*32 + lk*8, Ad + st*512);
      gll16(BT + (size_t)(bn + rb*16 + lr) * KDIM + k0 + kh*32 + lk*8, Bd + st*512);
    }
  };
  stage(0);
  stage(1);
  for (int t = 0; t < NIT; ++t) {
    if (t + 1 < NIT) asm volatile("s_waitcnt vmcnt(8)" ::: "memory");
    else             asm volatile("s_waitcnt vmcnt(0)" ::: "memory");
    asm volatile("s_barrier" ::: "memory");
    const __bf16* Ab = Asm + (t & 1) * 8192;
    const __bf16* Bb = Bsm + (t & 1) * 8192;
    #pragma unroll
    for (int ks = 0; ks < 2; ++ks) {
      bf16x8 a[4], b[4];
      #pragma unroll
      for (int mt = 0; mt < 4; ++mt) a[mt] = *(const bf16x8*)(Ab + ((wm*4+mt)*2+ks)*512 + lane*8);
      #pragma unroll
      for (int nt = 0; nt < 4; ++nt) b[nt] = *(const bf16x8*)(Bb + ((wn*4+nt)*2+ks)*512 + lane*8);
      __builtin_amdgcn_s_setprio(1);
      #pragma unroll
      for (int mt = 0; mt < 4; ++mt)
        #pragma unroll
        for (int nt = 0; nt < 4; ++nt)
          acc[mt][nt] = MFMA16(a[mt], b[nt], acc[mt][nt]);
      __builtin_amdgcn_s_setprio(0);
    }
    asm volatile("s_barrier" ::: "memory");
    if (t + 2 < NIT) stage(t + 2);
  }
}

// ---------------- QKV GEMM 256x256, 8-phase counted-vmcnt schedule ----------------
// A[8192x768] @ BT[2304x768]^T. Grid 288 (32 bm x 9 bn), 512 thr (8 waves: wm=w>>2,
// wn=w&3). Per-wave out: 128 rows x 64 cols as two 64-row strips (one per A-half)
// x four 16-col strips (two per B-half): row(mf) = (mf>>2)*128 + wm*64 + (mf&3)*16,
// col(nf) = (nf>>1)*128 + wn*32 + (nf&1)*16. LDS per operand [2 buf][2 half][16 st]
// [512] (64KB; subtile st = rowblk*2+khalf, 1KB, lane-contiguous -> conflict-free).
// Per K-tile T (buf=T&1): 4 phases q=(mh,nh): {ds-reads (12/4/8/0); stage one
// half-tile of the stream [A(T+1)h1, B(T+1)h1, A(T+2)h0, B(T+2)h0]; q3: vmcnt(4);
// barrier; setprio; 16 MFMA; setprio; barrier}. Ledger: half X(T)h staged >=4
// phases before first read; overwrite only after last reader's barrier; the q3
// vmcnt(4) leaves exactly this tile's p3/p4 stages (4 loads) outstanding and
// retires ALL of tile T+1. Prologue: A0h0,B0h0,A0h1,B0h1,A1h0,B1h0 -> vmcnt(4).
// Epilogue: Q/K direct scatter; V via LDS transpose in two 128-col halves.
__global__ __launch_bounds__(512, 2) void gemm_qkv_kernel(const __bf16* __restrict__ A,
                                                          const __bf16* __restrict__ BT,
                                                          __bf16* __restrict__ q,
                                                          __bf16* __restrict__ k,
                                                          __bf16* __restrict__ vt) {
  __shared__ __align__(16) __bf16 smem[65536];   // A 64KB + B 64KB; aliased transpose tile
  __bf16* Asm = smem;
  __bf16* Bsm = smem + 32768;
  const int lane = threadIdx.x & 63, wave = threadIdx.x >> 6;
  const int wm = wave >> 2, wn = wave & 3;          // 2 x 4 wave grid
  const int lr = lane & 15, lk = lane >> 4;
  const int quad = lane >> 4, c = lane & 15;
  // XCD swizzle: 288 blocks, 36/XCD (bijective; 288%8==0) = 4 bm-rows x 9 bn-cols
  const int wg = ((int)blockIdx.x & 7) * 36 + ((int)blockIdx.x >> 3);
  const int bm = (wg / 9) * 256, bn = (wg % 9) * 256;
  constexpr int KD = 768;
  constexpr int NT = 12;                            // K-tiles of 64

  // LDS offsets: op[buf][half][st][512]
  auto AOFF = [](int buf, int half, int st) { return ((buf*2 + half)*16 + st)*512; };

  // stage one half-tile (16KB): wave stages rowblk=wave, kh=0,1 (2 gll16/thread)
  auto stageA = [&](int T, int h) {
    const int b = T & 1;
    #pragma unroll
    for (int kh = 0; kh < 2; ++kh)
      gll16(A + (size_t)(bm + h*128 + wave*16 + lr) * KD + T*64 + kh*32 + lk*8,
            Asm + AOFF(b, h, wave*2 + kh));
  };
  auto stageB = [&](int T, int h) {
    const int b = T & 1;
    #pragma unroll
    for (int kh = 0; kh < 2; ++kh)
      gll16(BT + (size_t)(bn + h*128 + wave*16 + lr) * KD + T*64 + kh*32 + lk*8,
            Bsm + AOFF(b, h, wave*2 + kh));
  };

  f32x4 acc[8][4];
  #pragma unroll
  for (int i = 0; i < 8; ++i)
    #pragma unroll
    for (int j = 0; j < 4; ++j) acc[i][j] = zero4();

  // prologue: steady-state preload (stream order)
  stageA(0, 0); stageB(0, 0); stageA(0, 1); stageB(0, 1); stageA(1, 0); stageB(1, 0);
  asm volatile("s_waitcnt vmcnt(4)" ::: "memory");   // tile 0 complete
  asm volatile("s_barrier" ::: "memory");

  bf16x8 ac[4][2];     // a-frags for current mh (reused across the 2 nh phases)
  bf16x8 b0[2][2];     // b-frags nh=0 (read q0, reused q2)
  bf16x8 b1[2][2];     // b-frags nh=1 (read q1, reused q3)

  for (int T = 0; T < NT; ++T) {
    const int buf = T & 1;
    #pragma unroll
    for (int qp = 0; qp < 4; ++qp) {
      const int mh = qp >> 1, nh = qp & 1;
      // ds-loads for this phase (a at q0/q2; b-nh0 at q0; b-nh1 at q1)
      if (nh == 0) {
        #pragma unroll
        for (int mf = 0; mf < 4; ++mf)
          #pragma unroll
          for (int ks = 0; ks < 2; ++ks)
            ac[mf][ks] = *(const bf16x8*)(Asm + AOFF(buf, mh, (wm*4+mf)*2+ks) + lane*8);
      }
      if (qp == 0) {
        #pragma unroll
        for (int nf = 0; nf < 2; ++nf)
          #pragma unroll
          for (int ks = 0; ks < 2; ++ks)
            b0[nf][ks] = *(const bf16x8*)(Bsm + AOFF(buf, 0, (wn*2+nf)*2+ks) + lane*8);
      } else if (qp == 1) {
        #pragma unroll
        for (int nf = 0; nf < 2; ++nf)
          #pragma unroll
          for (int ks = 0; ks < 2; ++ks)
            b1[nf][ks] = *(const bf16x8*)(Bsm + AOFF(buf, 1, (wn*2+nf)*2+ks) + lane*8);
      }
      // stage stream: q0:A(T+1)h1  q1:B(T+1)h1  q2:A(T+2)h0  q3:B(T+2)h0
      if (qp == 0) { if (T + 1 < NT) stageA(T + 1, 1); }
      else if (qp == 1) { if (T + 1 < NT) stageB(T + 1, 1); }
      else if (qp == 2) { if (T + 2 < NT) stageA(T + 2, 0); }
      else {
        if (T + 2 < NT) stageB(T + 2, 0);
        // gate: tile T+1 fully resident (leaves only this tile's q2/q3 stages)
        if (T + 2 < NT)      asm volatile("s_waitcnt vmcnt(4)" ::: "memory");
        else if (T + 1 < NT) asm volatile("s_waitcnt vmcnt(0)" ::: "memory");
      }
      asm volatile("s_barrier" ::: "memory");
      __builtin_amdgcn_s_setprio(1);
      #pragma unroll
      for (int mf = 0; mf < 4; ++mf)
        #pragma unroll
        for (int nf = 0; nf < 2; ++nf)
          #pragma unroll
          for (int ks = 0; ks < 2; ++ks) {
            const bf16x8 bb = (nh == 0) ? b0[nf][ks] : b1[nf][ks];
            acc[mh*4+mf][nh*2+nf] = MFMA16(ac[mf][ks], bb, acc[mh*4+mf][nh*2+nf]);
          }
      __builtin_amdgcn_s_setprio(0);
      asm volatile("s_barrier" ::: "memory");
    }
  }

  // epilogue: row(mf) = (mf>>2)*128 + wm*64 + (mf&3)*16; col(nf) = (nf>>1)*128 + wn*32 + (nf&1)*16
  if (bn < 1536) {
    const float qscale = 0.125f * 1.44269504088896f;   // Q pre-scale for exp2 attn
    #pragma unroll
    for (int mf = 0; mf < 8; ++mf)
      #pragma unroll
      for (int nf = 0; nf < 4; ++nf) {
        const int col = bn + (nf>>1)*128 + wn*32 + (nf&1)*16 + c;   // 0..1535
        const int which = col >= 768 ? 1 : 0;
        const int within = col - which*768;
        const int h = within >> 6, d = within & 63;
        #pragma unroll
        for (int r = 0; r < 4; ++r) {
          const int row = bm + (mf>>2)*128 + wm*64 + (mf&3)*16 + quad*4 + r;
          const int b = row >> 11, n = row & 2047;
          const float vv = acc[mf][nf][r];
          const size_t idx = ((size_t)(b*12 + h) * 2048 + n) * 64 + d;  // [B,H,N,D]
          if (which == 0) q[idx] = (__bf16)(vv * qscale);
          else            k[idx] = (__bf16)vv;
        }
      }
  } else {
    // V: transpose 256x256 acc tile in LDS in two 128-col halves (pad 130)
    const int b = bm >> 11, n0 = bm & 2047;
    const int vo = bn - 1536;                 // 0, 256, 512
    #pragma unroll
    for (int ch2 = 0; ch2 < 2; ++ch2) {
      __syncthreads();                        // staging (or prev half) dead
      #pragma unroll
      for (int mf = 0; mf < 8; ++mf)
        #pragma unroll
        for (int nf2 = 0; nf2 < 2; ++nf2) {
          const int nf = ch2*2 + nf2;
          const int lcol = wn*32 + (nf&1)*16 + c;      // 0..127 within half
          #pragma unroll
          for (int r = 0; r < 4; ++r) {
            const int lrow = (mf>>2)*128 + wm*64 + (mf&3)*16 + quad*4 + r;
            smem[lrow*130 + lcol] = (__bf16)acc[mf][nf][r];
          }
        }
      __syncthreads();
      const int n = threadIdx.x & 255;
      const int csel = (threadIdx.x >> 8) & 1;
      #pragma unroll
      for (int pass = 0; pass < 64; ++pass) {
        const int lc = pass*2 + csel;                   // 0..127
        const int gcol = vo + ch2*128 + lc;             // 0..767
        const int h = gcol >> 6, d = gcol & 63;
        vt[((size_t)(b*12 + h)*64 + d)*2048 + n0 + n] = smem[n*130 + lc];
      }
    }
  }
}

// ---------------- Out-proj GEMM: o[8192,768] @ woutT[768,768]^T + f32 bias + f32 residual ----------------
// Grid: 384 linear blocks, XCD-swizzled (48/XCD = 8 bm-rows x 6 bn-cols; B 1.1MB in L2).
__global__ __launch_bounds__(256) void gemm_out_kernel(const __bf16* __restrict__ A,
                                                       const __bf16* __restrict__ BT,
                                                       const float* __restrict__ bias,
                                                       const float* __restrict__ resid,
                                                       float* __restrict__ out) {
  __shared__ __align__(16) __bf16 Asm[2*8192];
  __shared__ __align__(16) __bf16 Bsm[2*8192];
  const int lane = threadIdx.x & 63, wave = threadIdx.x >> 6;
  const int wg = ((int)blockIdx.x & 7) * 48 + ((int)blockIdx.x >> 3);
  const int bm = (wg / 6) * 128, bn = (wg % 6) * 128;
  f32x4 acc[4][4];
  #pragma unroll
  for (int i = 0; i < 4; ++i)
    #pragma unroll
    for (int j = 0; j < 4; ++j) acc[i][j] = zero4();
  gemm_mainloop<768>(A, BT, bm, bn, wave, lane, acc, Asm, Bsm);
  const int wm = wave >> 1, wn = wave & 1;
  const int quad = lane >> 4, c = lane & 15;
  #pragma unroll
  for (int mt = 0; mt < 4; ++mt)
    #pragma unroll
    for (int nt = 0; nt < 4; ++nt) {
      const int col = bn + wn*64 + nt*16 + c;
      #pragma unroll
      for (int r = 0; r < 4; ++r) {
        const int row = bm + wm*64 + mt*16 + quad*4 + r;
        out[(size_t)row*768 + col] = acc[mt][nt][r] + bias[col] + resid[(size_t)row*768 + col];
      }
    }
}

// ---------------- Flash attention: 1 block = (b,h) x 128 q-rows; 8 waves x 16 rows ----
// R19/R14 structure (settled optimum: ~67-69us at ~88% LDS-port util): swapped QK^T
// (S^T = mfma(K,Q), lane's S regs are its own q-row = lane&15); p = exp2(s)
// in-register; P->bf16 PV A-frag via cvt_pk + permlane32/16_swap. K/V double-
// buffered block-shared DMA (2 gll16/wave/stage), 32KB LDS, vmcnt(2) steady.
// Row-sum via ones-operand MFMA. [R17/R18/R22: any K/V-to-registers variant
// spills or serializes -- do not reopen.]
__global__ __launch_bounds__(512, 6) void attn_kernel(const __bf16* __restrict__ q,
                                                      const __bf16* __restrict__ k,
                                                      const __bf16* __restrict__ vt,
                                                      __bf16* __restrict__ o) {
  const int xcd = blockIdx.x & 7, i = blockIdx.x >> 3;
  const int bh = xcd * 6 + (i >> 4);   // 0..47
  const int qt = i & 15;               // 16 q-tiles of 128 rows
  const int lane = threadIdx.x & 63, wave = threadIdx.x >> 6;   // wave 0..7
  const int c = lane & 15, quad = lane >> 4;
  const int lr = lane & 15, lk = lane >> 4;
  const int q0 = qt*128 + wave*16;

  const __bf16* qb = q  + ((size_t)bh*2048 + q0) * 64;
  const __bf16* kb = k  + (size_t)bh * 2048 * 64;
  const __bf16* vb = vt + (size_t)bh * 64 * 2048;

  __shared__ __align__(16) __bf16 Ksm[2][4096];
  __shared__ __align__(16) __bf16 Vsm[2][4096];

  bf16x8 aq[2];
  aq[0] = *(const bf16x8*)(qb + (size_t)c*64 + quad*8);
  aq[1] = *(const bf16x8*)(qb + (size_t)c*64 + 32 + quad*8);

  const __bf16 one = (__bf16)1.0f;
  bf16x8 vones;
  #pragma unroll
  for (int j = 0; j < 8; ++j) vones[j] = one;

  f32x4 od[4];
  f32x4 clacc = zero4();
  #pragma unroll
  for (int r = 0; r < 4; ++r) od[r] = zero4();

  auto stage = [&](int it) {
    const int kt = it * 64;
    __bf16* Ks = Ksm[it & 1];
    __bf16* Vs = Vsm[it & 1];
    gll16(kb + (size_t)(kt + (wave>>1)*16 + lr) * 64 + (wave&1)*32 + lk*8,  Ks + wave*512);
    gll16(vb + (size_t)((wave>>1)*16 + lr) * 2048 + kt + (wave&1)*32 + lk*8, Vs + wave*512);
  };

  stage(0);
  stage(1);

  for (int it = 0; it < 32; ++it) {
    const __bf16* Ks = Ksm[it & 1];
    const __bf16* Vs = Vsm[it & 1];
    if (it < 31) asm volatile("s_waitcnt vmcnt(2)" ::: "memory");
    else         asm volatile("s_waitcnt vmcnt(0)" ::: "memory");
    asm volatile("s_barrier" ::: "memory");
    #pragma unroll
    for (int ch = 0; ch < 2; ++ch) {
      unsigned pk[2][2];
      #pragma unroll
      for (int t2 = 0; t2 < 2; ++t2) {
        const int t = ch*2 + t2;
        const bf16x8 ka0 = *(const bf16x8*)(Ks + (t*2+0)*512 + lane*8);
        const bf16x8 ka1 = *(const bf16x8*)(Ks + (t*2+1)*512 + lane*8);
        f32x4 z = zero4();
        __builtin_amdgcn_s_setprio(1);
        z = MFMA16(ka0, aq[0], z);
        z = MFMA16(ka1, aq[1], z);
        __builtin_amdgcn_s_setprio(0);
        const float p0 = __builtin_amdgcn_exp2f(z[0]);
        const float p1 = __builtin_amdgcn_exp2f(z[1]);
        const float p2 = __builtin_amdgcn_exp2f(z[2]);
        const float p3 = __builtin_amdgcn_exp2f(z[3]);
        pk[t2][0] = cvt_pk_bf16(p0, p1);
        pk[t2][1] = cvt_pk_bf16(p2, p3);
      }
      unsigned s0 = pk[0][0], s2 = pk[1][0];
      permlane32_swap(s0, s2);
      permlane16_swap(s0, s2);
      unsigned s1 = pk[0][1], s3 = pk[1][1];
      permlane32_swap(s1, s3);
      permlane16_swap(s1, s3);
      u32x4 w4; w4.x = s0; w4.y = s1; w4.z = s2; w4.w = s3;
      const bf16x8 pa = __builtin_bit_cast(bf16x8, w4);
      __builtin_amdgcn_s_setprio(1);
      #pragma unroll
      for (int dt = 0; dt < 4; ++dt) {
        const bf16x8 bv = *(const bf16x8*)(Vs + (dt*2+ch)*512 + lane*8);
        od[dt] = MFMA16(pa, bv, od[dt]);
      }
      clacc = MFMA16(pa, vones, clacc);
      __builtin_amdgcn_s_setprio(0);
    }
    asm volatile("s_barrier" ::: "memory");
    if (it + 2 < 32) stage(it + 2);
  }
  const int b = bh / 12, h = bh % 12;
  float rl[4];
  #pragma unroll
  for (int r = 0; r < 4; ++r) rl[r] = 1.f / clacc[r];
  #pragma unroll
  for (int dt = 0; dt < 4; ++dt)
    #pragma unroll
    for (int r = 0; r < 4; ++r) {
      const int n = q0 + quad*4 + r;
      const int col = h*64 + dt*16 + c;
      o[((size_t)b*2048 + n)*768 + col] = (__bf16)(od[dt][r] * rl[r]);
    }
}

extern "C" void kernel_launch(void* const* d_in, const int* in_sizes, int n_in,
                              void* d_out, int out_size, void* d_ws, size_t ws_size,
                              hipStream_t stream) {
  const float* img   = (const float*)d_in[0];
  const float* gamma = (const float*)d_in[1];
  const float* beta  = (const float*)d_in[2];
  const float* wqkv  = (const float*)d_in[3];
  const float* wout  = (const float*)d_in[4];
  const float* bout  = (const float*)d_in[5];
  float* out = (float*)d_out;

  __bf16* ws = (__bf16*)d_ws;
  size_t off = 0;
  __bf16* xn    = ws + off; off += (size_t)8192*768;   // LN output (bf16)
  __bf16* wqkvT = ws + off; off += (size_t)2304*768;   // w_qkv^T (bf16)
  __bf16* woutT = ws + off; off += (size_t)768*768;    // w_out^T (bf16)
  __bf16* qs    = ws + off; off += (size_t)48*2048*64; // Q*0.125*log2e [B,H,N,D]
  __bf16* ks    = ws + off; off += (size_t)48*2048*64; // K     [B,H,N,D]
  __bf16* vts   = ws + off; off += (size_t)48*64*2048; // V^T   [B,H,D,N]
  __bf16* os    = ws + off; off += (size_t)8192*768;   // attn out [B,N,C]

  ln_kernel<<<8192, 256, 0, stream>>>(img, gamma, beta, xn);
  transpose_kernel<<<dim3(72, 24), 256, 0, stream>>>(wqkv, wqkvT, 768, 2304);
  transpose_kernel<<<dim3(24, 24), 256, 0, stream>>>(wout, woutT, 768, 768);
  gemm_qkv_kernel<<<288, 512, 0, stream>>>(xn, wqkvT, qs, ks, vts);
  attn_kernel<<<768, 512, 0, stream>>>(qs, ks, vts, os);
  gemm_out_kernel<<<384, 256, 0, stream>>>(os, woutT, bout, img, out);
}

// Round 13
// 237.282 us; speedup vs baseline: 1.6217x; 1.0279x over previous
//
#include <hip/hip_runtime.h>

// Problem: B=4, N=2048, C=768, H=12, D=64. I/O f32; internals bf16 MFMA + f32 acc.
// Pipeline: prep(LN + both weight transposes, FUSED) -> QKV GEMM -> flash attn ->
//           out-proj GEMM (+bias +residual).
// R24: (a) gemm_qkv reverted to R19 2-phase BK=64 128^2 (proven 66.9us; R23's
//   8-phase 256^2 ran blocks ~2x more efficiently but grid 288 on 256 CUs =
//   1-block/CU quantization -> 2x tail; 2304/256=9 cols is un-balanceable).
//   (b) NEW: ln + transpose(wqkv) + transpose(wout) fused into ONE kernel
//   (blockIdx-partitioned; whole blocks per branch). Kernel-time sum ~170us vs
//   239 total -> ~65us in 5 inter-kernel boundaries; 6 launches -> 4.
//   attn/gemm_out = R19 (proven).

typedef __bf16 bf16x8 __attribute__((ext_vector_type(8)));
typedef float  f32x4  __attribute__((ext_vector_type(4)));
typedef unsigned int u32x4 __attribute__((ext_vector_type(4)));

#define MFMA16(a,b,c) __builtin_amdgcn_mfma_f32_16x16x32_bf16((a),(b),(c),0,0,0)

__device__ inline f32x4 zero4() { f32x4 z = {0.f,0.f,0.f,0.f}; return z; }

// async global->LDS, 16B per lane; lds dest is wave-uniform base + lane*16
__device__ inline void gll16(const __bf16* g, __bf16* l) {
  __builtin_amdgcn_global_load_lds((const __attribute__((address_space(1))) unsigned int*)g,
                                   (__attribute__((address_space(3))) unsigned int*)l,
                                   16, 0, 0);
}

// pack two f32 -> bf16x2 (RNE); no builtin on gfx950, inline asm per guide
__device__ inline unsigned cvt_pk_bf16(float lo, float hi) {
  unsigned r;
  asm("v_cvt_pk_bf16_f32 %0, %1, %2" : "=v"(r) : "v"(lo), "v"(hi));
  return r;
}
// a[32:63] <-> b[0:31]
__device__ inline void permlane32_swap(unsigned &a, unsigned &b) {
  asm("v_permlane32_swap_b32 %0, %1" : "+v"(a), "+v"(b));
}
// a[16:31]<->b[0:15], a[48:63]<->b[32:47]
__device__ inline void permlane16_swap(unsigned &a, unsigned &b) {
  asm("v_permlane16_swap_b32 %0, %1" : "+v"(a), "+v"(b));
}

// ---------------- Fused prep: LN (blocks 0..8191) + transpose wqkv (next 1728)
// ---------------- + transpose wout (next 576). One launch instead of three.
__global__ __launch_bounds__(256) void prep_kernel(const float* __restrict__ x,
                                                   const float* __restrict__ g,
                                                   const float* __restrict__ bt,
                                                   __bf16* __restrict__ xn,
                                                   const float* __restrict__ wqkv,
                                                   __bf16* __restrict__ wqkvT,
                                                   const float* __restrict__ wout,
                                                   __bf16* __restrict__ woutT) {
  __shared__ float t[32][33];      // transpose tile (ln uses first 8 floats)
  const int bid = blockIdx.x;
  const int tid = threadIdx.x;
  if (bid < 8192) {
    // ---- LayerNorm row ----
    const int row = bid;
    const float* xr = x + (size_t)row * 768;
    float v[3]; float s = 0.f, ss = 0.f;
    #pragma unroll
    for (int i = 0; i < 3; ++i) { float f = xr[tid + 256*i]; v[i] = f; s += f; ss += f*f; }
    #pragma unroll
    for (int m = 32; m >= 1; m >>= 1) { s += __shfl_xor(s, m, 64); ss += __shfl_xor(ss, m, 64); }
    float* red = &t[0][0];
    const int wave = tid >> 6;
    if ((tid & 63) == 0) { red[wave] = s; red[4 + wave] = ss; }
    __syncthreads();
    s  = red[0] + red[1] + red[2] + red[3];
    ss = red[4] + red[5] + red[6] + red[7];
    const float mu  = s * (1.f/768.f);
    const float var = ss * (1.f/768.f) - mu*mu;
    const float inv = rsqrtf(var + 1e-5f);
    __bf16* xo = xn + (size_t)row * 768;
    #pragma unroll
    for (int i = 0; i < 3; ++i) {
      const int c0 = tid + 256*i;
      xo[c0] = (__bf16)((v[i] - mu) * inv * g[c0] + bt[c0]);
    }
  } else {
    // ---- 32x32 tiled transpose + f32->bf16 ----
    const float* in; __bf16* out; int R, C, bx, by;
    if (bid < 8192 + 1728) {
      const int tt = bid - 8192;
      in = wqkv; out = wqkvT; R = 768; C = 2304;
      bx = tt % 72; by = tt / 72;
    } else {
      const int tt = bid - (8192 + 1728);
      in = wout; out = woutT; R = 768; C = 768;
      bx = tt % 24; by = tt / 24;
    }
    const int tx = tid & 31, ty = tid >> 5;
    const int c0 = bx * 32, r0 = by * 32;
    #pragma unroll
    for (int p = 0; p < 4; ++p) t[ty + 8*p][tx] = in[(size_t)(r0 + ty + 8*p) * C + c0 + tx];
    __syncthreads();
    #pragma unroll
    for (int p = 0; p < 4; ++p) out[(size_t)(c0 + ty + 8*p) * R + r0 + tx] = (__bf16)t[tx][ty + 8*p];
  }
}

// ---------------- GEMM mainloop BK=64, double-buffered: C[128x128] = A @ BT^T (bf16) ----
// LDS per buffer: 16 subtiles of 16x32 per operand (st = rowblk*2 + khalf, 1KB each);
// two buffers per operand (64KB total). Wave stages 4 A + 4 B subtiles (8 gll16).
// Steady state: compute buf[t&1] while stage(t+1)'s 8 loads are in flight
// (vmcnt(8) at top, never 0 mid-loop); stage(t+2) issued after the read-done barrier.
template<int KDIM>
__device__ inline void gemm_mainloop(const __bf16* __restrict__ A, const __bf16* __restrict__ BT,
                                     int bm, int bn, int wave, int lane,
                                     f32x4 acc[4][4], __bf16* Asm, __bf16* Bsm) {
  const int wm = wave >> 1, wn = wave & 1;
  const int lr = lane & 15, lk = lane >> 4;
  constexpr int NIT = KDIM / 64;
  auto stage = [&](int t) {
    const int k0 = t * 64;
    __bf16* Ad = Asm + (t & 1) * 8192;
    __bf16* Bd = Bsm + (t & 1) * 8192;
    #pragma unroll
    for (int s2 = 0; s2 < 4; ++s2) {
      const int st = wave * 4 + s2;
      const int rb = st >> 1, kh = st & 1;
      gll16(A  + (size_t)(bm + rb*16 + lr) * KDIM + k0 + kh*32 + lk*8, Ad + st*512);
      gll16(BT + (size_t)(bn + rb*16 + lr) * KDIM + k0 + kh*32 + lk*8, Bd + st*512);
    }
  };
  stage(0);
  stage(1);
  for (int t = 0; t < NIT; ++t) {
    if (t + 1 < NIT) asm volatile("s_waitcnt vmcnt(8)" ::: "memory");
    else             asm volatile("s_waitcnt vmcnt(0)" ::: "memory");
    asm volatile("s_barrier" ::: "memory");      // all waves' stage(t) visible
    const __bf16* Ab = Asm + (t & 1) * 8192;
    const __bf16* Bb = Bsm + (t & 1) * 8192;
    #pragma unroll
    for (int ks = 0; ks < 2; ++ks) {
      bf16x8 a[4], b[4];
      #pragma unroll
      for (int mt = 0; mt < 4; ++mt) a[mt] = *(const bf16x8*)(Ab + ((wm*4+mt)*2+ks)*512 + lane*8);
      #pragma unroll
      for (int nt = 0; nt < 4; ++nt) b[nt] = *(const bf16x8*)(Bb + ((wn*4+nt)*2+ks)*512 + lane*8);
      __builtin_amdgcn_s_setprio(1);
      #pragma unroll
      for (int mt = 0; mt < 4; ++mt)
        #pragma unroll
        for (int nt = 0; nt < 4; ++nt)
          acc[mt][nt] = MFMA16(a[mt], b[nt], acc[mt][nt]);
      __builtin_amdgcn_s_setprio(0);
    }
    asm volatile("s_barrier" ::: "memory");      // all waves done reading buf[t&1]
    if (t + 2 < NIT) stage(t + 2);               // overwrite buf[t&1] for t+2
  }
}

// ---------------- QKV GEMM: xn[8192,768] @ wqkvT[2304,768]^T ----------------
// Q/K blocks (bn<1536) store direct. V blocks (bn>=1536) transpose the 128x128 acc
// tile in LDS (pad-66) and store V^T [B,H,D,N] coalesced. Transpose tile aliases staging.
// Grid: 1152 linear blocks, XCD-swizzled (144/XCD = 8 bm-rows x 18 bn-cols ->
// B panel 3.5MB ~resident in its 4MB L2). [R20/R21/R23: BK=32, 3-stage, and
// 8-phase 256^2 all ~67us -- 2-phase 128^2 is the practical optimum here;
// 256^2 grid (288) cannot balance on 256 CUs.]
__global__ __launch_bounds__(256) void gemm_qkv_kernel(const __bf16* __restrict__ A,
                                                       const __bf16* __restrict__ BT,
                                                       __bf16* __restrict__ q,
                                                       __bf16* __restrict__ k,
                                                       __bf16* __restrict__ vt) {
  __shared__ __align__(16) __bf16 smem[4*8192];   // A dbuf + B dbuf (64KB); aliased transpose tile
  __bf16* Asm = smem;
  __bf16* Bsm = smem + 2*8192;
  const int lane = threadIdx.x & 63, wave = threadIdx.x >> 6;
  const int wg = ((int)blockIdx.x & 7) * 144 + ((int)blockIdx.x >> 3);
  const int bm = (wg / 18) * 128, bn = (wg % 18) * 128;
  f32x4 acc[4][4];
  #pragma unroll
  for (int i = 0; i < 4; ++i)
    #pragma unroll
    for (int j = 0; j < 4; ++j) acc[i][j] = zero4();
  gemm_mainloop<768>(A, BT, bm, bn, wave, lane, acc, Asm, Bsm);
  const int wm = wave >> 1, wn = wave & 1;
  const int quad = lane >> 4, c = lane & 15;
  if (bn < 1536) {
    // Q pre-scale: 1/sqrt(64) * log2(e) so attention does p = exp2(score) natively
    const float qscale = 0.125f * 1.44269504088896f;
    #pragma unroll
    for (int mt = 0; mt < 4; ++mt)
      #pragma unroll
      for (int nt = 0; nt < 4; ++nt) {
        const int col = bn + wn*64 + nt*16 + c;           // 0..1535
        const int which = col >= 768 ? 1 : 0;
        const int within = col - which*768;
        const int h = within >> 6, d = within & 63;
        #pragma unroll
        for (int r = 0; r < 4; ++r) {
          const int row = bm + wm*64 + mt*16 + quad*4 + r; // 0..8191
          const int b = row >> 11, n = row & 2047;
          const float vv = acc[mt][nt][r];
          const size_t idx = ((size_t)(b*12 + h) * 2048 + n) * 64 + d;  // [B,H,N,D]
          if (which == 0) q[idx] = (__bf16)(vv * qscale);
          else            k[idx] = (__bf16)vv;
        }
      }
  } else {
    __syncthreads();   // staging buffers dead; reuse as transpose tile
    #pragma unroll
    for (int mt = 0; mt < 4; ++mt)
      #pragma unroll
      for (int nt = 0; nt < 4; ++nt) {
        const int lcol = wn*64 + nt*16 + c;
        #pragma unroll
        for (int r = 0; r < 4; ++r) {
          const int lrow = wm*64 + mt*16 + quad*4 + r;
          smem[lrow*66 + lcol] = (__bf16)acc[mt][nt][r];
        }
      }
    __syncthreads();
    const int b = bm >> 11, n0 = bm & 2047;
    const int vo = bn - 1536;                // 0..639 (V-region col offset)
    const int n = threadIdx.x & 127;
    const int csel = threadIdx.x >> 7;
    #pragma unroll
    for (int pass = 0; pass < 64; ++pass) {
      const int lc = pass*2 + csel;          // 0..127
      const int gcol = vo + lc;              // 0..767
      const int h = gcol >> 6, d = gcol & 63;
      vt[((size_t)(b*12 + h)*64 + d)*2048 + n0 + n] = smem[n*66 + lc];
    }
  }
}

// ---------------- Out-proj GEMM: o[8192,768] @ woutT[768,768]^T + f32 bias + f32 residual ----------------
// Grid: 384 linear blocks, XCD-swizzled (48/XCD = 8 bm-rows x 6 bn-cols; B 1.1MB in L2).
__global__ __launch_bounds__(256) void gemm_out_kernel(const __bf16* __restrict__ A,
                                                       const __bf16* __restrict__ BT,
                                                       const float* __restrict__ bias,
                                                       const float* __restrict__ resid,
                                                       float* __restrict__ out) {
  __shared__ __align__(16) __bf16 Asm[2*8192];
  __shared__ __align__(16) __bf16 Bsm[2*8192];
  const int lane = threadIdx.x & 63, wave = threadIdx.x >> 6;
  const int wg = ((int)blockIdx.x & 7) * 48 + ((int)blockIdx.x >> 3);
  const int bm = (wg / 6) * 128, bn = (wg % 6) * 128;
  f32x4 acc[4][4];
  #pragma unroll
  for (int i = 0; i < 4; ++i)
    #pragma unroll
    for (int j = 0; j < 4; ++j) acc[i][j] = zero4();
  gemm_mainloop<768>(A, BT, bm, bn, wave, lane, acc, Asm, Bsm);
  const int wm = wave >> 1, wn = wave & 1;
  const int quad = lane >> 4, c = lane & 15;
  #pragma unroll
  for (int mt = 0; mt < 4; ++mt)
    #pragma unroll
    for (int nt = 0; nt < 4; ++nt) {
      const int col = bn + wn*64 + nt*16 + c;
      #pragma unroll
      for (int r = 0; r < 4; ++r) {
        const int row = bm + wm*64 + mt*16 + quad*4 + r;
        out[(size_t)row*768 + col] = acc[mt][nt][r] + bias[col] + resid[(size_t)row*768 + col];
      }
    }
}

// ---------------- Flash attention: 1 block = (b,h) x 128 q-rows; 8 waves x 16 rows ----
// R19/R14 structure (settled optimum: ~67-69us at ~88% LDS-port util): swapped QK^T
// (S^T = mfma(K,Q), lane's S regs are its own q-row = lane&15); p = exp2(s)
// in-register; P->bf16 PV A-frag via cvt_pk + permlane32/16_swap. K/V double-
// buffered block-shared DMA (2 gll16/wave/stage), 32KB LDS, vmcnt(2) steady.
// Row-sum via ones-operand MFMA. [R17/R18/R22: any K/V-to-registers variant
// spills or serializes -- do not reopen.]
__global__ __launch_bounds__(512, 6) void attn_kernel(const __bf16* __restrict__ q,
                                                      const __bf16* __restrict__ k,
                                                      const __bf16* __restrict__ vt,
                                                      __bf16* __restrict__ o) {
  const int xcd = blockIdx.x & 7, i = blockIdx.x >> 3;
  const int bh = xcd * 6 + (i >> 4);   // 0..47
  const int qt = i & 15;               // 16 q-tiles of 128 rows
  const int lane = threadIdx.x & 63, wave = threadIdx.x >> 6;   // wave 0..7
  const int c = lane & 15, quad = lane >> 4;
  const int lr = lane & 15, lk = lane >> 4;
  const int q0 = qt*128 + wave*16;

  const __bf16* qb = q  + ((size_t)bh*2048 + q0) * 64;
  const __bf16* kb = k  + (size_t)bh * 2048 * 64;
  const __bf16* vb = vt + (size_t)bh * 64 * 2048;

  __shared__ __align__(16) __bf16 Ksm[2][4096];
  __shared__ __align__(16) __bf16 Vsm[2][4096];

  bf16x8 aq[2];
  aq[0] = *(const bf16x8*)(qb + (size_t)c*64 + quad*8);
  aq[1] = *(const bf16x8*)(qb + (size_t)c*64 + 32 + quad*8);

  const __bf16 one = (__bf16)1.0f;
  bf16x8 vones;
  #pragma unroll
  for (int j = 0; j < 8; ++j) vones[j] = one;

  f32x4 od[4];
  f32x4 clacc = zero4();
  #pragma unroll
  for (int r = 0; r < 4; ++r) od[r] = zero4();

  auto stage = [&](int it) {
    const int kt = it * 64;
    __bf16* Ks = Ksm[it & 1];
    __bf16* Vs = Vsm[it & 1];
    gll16(kb + (size_t)(kt + (wave>>1)*16 + lr) * 64 + (wave&1)*32 + lk*8,  Ks + wave*512);
    gll16(vb + (size_t)((wave>>1)*16 + lr) * 2048 + kt + (wave&1)*32 + lk*8, Vs + wave*512);
  };

  stage(0);
  stage(1);

  for (int it = 0; it < 32; ++it) {
    const __bf16* Ks = Ksm[it & 1];
    const __bf16* Vs = Vsm[it & 1];
    if (it < 31) asm volatile("s_waitcnt vmcnt(2)" ::: "memory");
    else         asm volatile("s_waitcnt vmcnt(0)" ::: "memory");
    asm volatile("s_barrier" ::: "memory");
    #pragma unroll
    for (int ch = 0; ch < 2; ++ch) {
      unsigned pk[2][2];
      #pragma unroll
      for (int t2 = 0; t2 < 2; ++t2) {
        const int t = ch*2 + t2;
        const bf16x8 ka0 = *(const bf16x8*)(Ks + (t*2+0)*512 + lane*8);
        const bf16x8 ka1 = *(const bf16x8*)(Ks + (t*2+1)*512 + lane*8);
        f32x4 z = zero4();
        __builtin_amdgcn_s_setprio(1);
        z = MFMA16(ka0, aq[0], z);
        z = MFMA16(ka1, aq[1], z);
        __builtin_amdgcn_s_setprio(0);
        const float p0 = __builtin_amdgcn_exp2f(z[0]);
        const float p1 = __builtin_amdgcn_exp2f(z[1]);
        const float p2 = __builtin_amdgcn_exp2f(z[2]);
        const float p3 = __builtin_amdgcn_exp2f(z[3]);
        pk[t2][0] = cvt_pk_bf16(p0, p1);
        pk[t2][1] = cvt_pk_bf16(p2, p3);
      }
      unsigned s0 = pk[0][0], s2 = pk[1][0];
      permlane32_swap(s0, s2);
      permlane16_swap(s0, s2);
      unsigned s1 = pk[0][1], s3 = pk[1][1];
      permlane32_swap(s1, s3);
      permlane16_swap(s1, s3);
      u32x4 w4; w4.x = s0; w4.y = s1; w4.z = s2; w4.w = s3;
      const bf16x8 pa = __builtin_bit_cast(bf16x8, w4);
      __builtin_amdgcn_s_setprio(1);
      #pragma unroll
      for (int dt = 0; dt < 4; ++dt) {
        const bf16x8 bv = *(const bf16x8*)(Vs + (dt*2+ch)*512 + lane*8);
        od[dt] = MFMA16(pa, bv, od[dt]);
      }
      clacc = MFMA16(pa, vones, clacc);
      __builtin_amdgcn_s_setprio(0);
    }
    asm volatile("s_barrier" ::: "memory");
    if (it + 2 < 32) stage(it + 2);
  }
  const int b = bh / 12, h = bh % 12;
  float rl[4];
  #pragma unroll
  for (int r = 0; r < 4; ++r) rl[r] = 1.f / clacc[r];
  #pragma unroll
  for (int dt = 0; dt < 4; ++dt)
    #pragma unroll
    for (int r = 0; r < 4; ++r) {
      const int n = q0 + quad*4 + r;
      const int col = h*64 + dt*16 + c;
      o[((size_t)b*2048 + n)*768 + col] = (__bf16)(od[dt][r] * rl[r]);
    }
}

extern "C" void kernel_launch(void* const* d_in, const int* in_sizes, int n_in,
                              void* d_out, int out_size, void* d_ws, size_t ws_size,
                              hipStream_t stream) {
  const float* img   = (const float*)d_in[0];
  const float* gamma = (const float*)d_in[1];
  const float* beta  = (const float*)d_in[2];
  const float* wqkv  = (const float*)d_in[3];
  const float* wout  = (const float*)d_in[4];
  const float* bout  = (const float*)d_in[5];
  float* out = (float*)d_out;

  __bf16* ws = (__bf16*)d_ws;
  size_t off = 0;
  __bf16* xn    = ws + off; off += (size_t)8192*768;   // LN output (bf16)
  __bf16* wqkvT = ws + off; off += (size_t)2304*768;   // w_qkv^T (bf16)
  __bf16* woutT = ws + off; off += (size_t)768*768;    // w_out^T (bf16)
  __bf16* qs    = ws + off; off += (size_t)48*2048*64; // Q*0.125*log2e [B,H,N,D]
  __bf16* ks    = ws + off; off += (size_t)48*2048*64; // K     [B,H,N,D]
  __bf16* vts   = ws + off; off += (size_t)48*64*2048; // V^T   [B,H,D,N]
  __bf16* os    = ws + off; off += (size_t)8192*768;   // attn out [B,N,C]

  // fused prep: 8192 LN rows + 1728 wqkv-transpose tiles + 576 wout-transpose tiles
  prep_kernel<<<8192 + 1728 + 576, 256, 0, stream>>>(img, gamma, beta, xn,
                                                     wqkv, wqkvT, wout, woutT);
  gemm_qkv_kernel<<<1152, 256, 0, stream>>>(xn, wqkvT, qs, ks, vts);
  attn_kernel<<<768, 512, 0, stream>>>(qs, ks, vts, os);
  gemm_out_kernel<<<384, 256, 0, stream>>>(os, woutT, bout, img, out);
}